// Round 4
// baseline (802.814 us; speedup 1.0000x reference)
//
#include <hip/hip_runtime.h>

// CIN_51539607712 — R4: 32x32x16 MFMA, 16 waves/block (4/SIMD), kq-tree epilogue.
// out[r,n] = sum_h xl[r,h] * Y_h[r,n],  Y_h[r,n] = sum_m x0[r,m] W[h*32+m,n].
// Y via 3 bf16 MFMAs (x0h*wh + x0h*wl + x0l*wh); acc += xl (.) Y in fp32.
// Block = 64 rows x 128 cols, 1024 thr = 16 waves: (kq = w>>2, nq = w&3).
// Wave: 64 rows (2 tiles of 32) x 32 cols x K/4. W pre-split+packed as 2 KB
// sub-k units in exact global_load_lds order; per-wave 2-deep ring (2x2KB),
// barrier-free K-loop (per-wave vmcnt(0)). LDS = 64 KB. Activations transposed.

typedef unsigned int u32;
typedef __attribute__((ext_vector_type(8))) short short8;
typedef __attribute__((ext_vector_type(4))) float f32x4;
typedef __attribute__((ext_vector_type(16))) float f32x16;
typedef __attribute__((ext_vector_type(4))) u32 u32x4;

#define R_TOTAL 16384
#define GLOBAL_AS __attribute__((address_space(1)))
#define LDS_AS __attribute__((address_space(3)))

union PackU { u32 u[4]; short8 s; };
union PackB { u32x4 v; short8 s; };

__device__ __forceinline__ u32 pack_trunc(float a, float b) {
  return __builtin_amdgcn_perm(__float_as_uint(b), __float_as_uint(a), 0x07060302u);
}

// ---------------- prep: X0T[m][b*16+d] = in[b][m][d]  (32 x 16384) ----------
__global__ __launch_bounds__(256) void build_x0t(const float* __restrict__ in,
                                                 float* __restrict__ x0t) {
  __shared__ float t[4096];
  const int tid = threadIdx.x;
  const int b0 = blockIdx.x * 8;
  #pragma unroll
  for (int rep = 0; rep < 4; ++rep) {
    int idx = tid + rep * 256;
    *(float4*)&t[idx * 4] = *(const float4*)&in[(size_t)b0 * 512 + idx * 4];
  }
  __syncthreads();
  #pragma unroll
  for (int rep = 0; rep < 4; ++rep) {
    int idx = tid + rep * 256;     // 0..1023: m(32) x bl(8) x dq(4)
    int m = idx >> 5, rem = idx & 31;
    int bl = rem >> 2, dq = rem & 3;
    *(float4*)&x0t[(size_t)m * R_TOTAL + (b0 + bl) * 16 + dq * 4] =
        *(const float4*)&t[bl * 512 + m * 16 + dq * 4];
  }
}

// ---------------- prep: split+pack W into 2 KB sub-k units -------------------
// Unit (h, nq, s) at u32-offset ((h*4+nq)*2+s)*512. Entry e = p*64+q2*32+n
// (16 B): bf16 pairs (k=2r,2r+1) of part p of W[h*32+s*16+q2*8+(0..7)][nq*32+n].
__global__ __launch_bounds__(256) void swizzle_w(const float* __restrict__ W,
                                                 u32* __restrict__ wt) {
  __shared__ float wl[32 * 132];
  const int tid = threadIdx.x;
  const int h = blockIdx.x;
  #pragma unroll
  for (int rep = 0; rep < 4; ++rep) {
    int idx = tid + rep * 256;          // 1024 float4 = 32 k x 32 f4
    int kk = idx >> 5, c4 = idx & 31;
    *(float4*)&wl[kk * 132 + c4 * 4] =
        *(const float4*)&W[(size_t)(h * 32 + kk) * 128 + c4 * 4];
  }
  __syncthreads();
  #pragma unroll
  for (int rep = 0; rep < 4; ++rep) {
    int e = tid + rep * 256;            // 1024 entries (4 nq x 2 s x 128)
    int nq = e >> 8, rem = e & 255;
    int s = rem >> 7, p = (rem >> 6) & 1, q2 = (rem >> 5) & 1, n = rem & 31;
    int k0 = s * 16 + q2 * 8, col = nq * 32 + n;
    u32 o[4];
    #pragma unroll
    for (int r = 0; r < 4; ++r) {
      float v0 = wl[(k0 + 2 * r) * 132 + col];
      float v1 = wl[(k0 + 2 * r + 1) * 132 + col];
      if (p == 1) {
        v0 -= __uint_as_float(__float_as_uint(v0) & 0xffff0000u);
        v1 -= __uint_as_float(__float_as_uint(v1) & 0xffff0000u);
      }
      o[r] = pack_trunc(v0, v1);
    }
    *(u32x4*)(wt + (((size_t)h * 4 + nq) * 2 + s) * 512 + (rem & 127) * 4) =
        u32x4{o[0], o[1], o[2], o[3]};
  }
}

// ---------------- per-wave sub-k staging: 2048 B via global_load_lds ---------
__device__ __forceinline__ void stage2k(const u32* g, u32* l, int lane) {
  const GLOBAL_AS u32* gp = (const GLOBAL_AS u32*)g;
  LDS_AS u32* lp = (LDS_AS u32*)l;
  __builtin_amdgcn_global_load_lds(gp + lane * 4, lp, 16, 0, 0);
  __builtin_amdgcn_global_load_lds(gp + 256 + lane * 4, lp + 256, 16, 0, 0);
}

// ---------------- main layer kernel ----------------
template <int NT, bool RELU, bool STORE_X>
__global__ __launch_bounds__(1024, 4) void layer_mfma(
    const float* __restrict__ xt,    // NT x R (transposed prev activation)
    const float* __restrict__ x0t,   // 32 x R
    const u32* __restrict__ wt,      // NT*8 sub-k units (512 u32 each)
    const float* __restrict__ bias,  // 128
    float* __restrict__ xoutT,       // 128 x R (if STORE_X)
    float* __restrict__ osum)        // d_out + layer offset, stride 384
{
  constexpr int HK = NT / 4;          // h-values per K-quarter
  __shared__ u32 smem[16384];         // 64 KB: 16 waves x (2 x 2KB ring)

  const int tid = threadIdx.x;
  const int w = tid >> 6, lane = tid & 63;
  const int kq = w >> 2, nq = w & 3;
  const int ln31 = lane & 31, q2 = lane >> 5;
  const int r0 = blockIdx.x * 64;
  u32* mybuf = smem + w * 1024;

  // ---- loop-invariant A fragments: x0 splits. A[m=ln31][k=q2*8+j] per (t,s).
  PackU Ah[2][2], Al[2][2];
  #pragma unroll
  for (int t = 0; t < 2; ++t)
    #pragma unroll
    for (int s = 0; s < 2; ++s) {
      const float* src = x0t + (size_t)(s * 16 + q2 * 8) * R_TOTAL + r0 + t * 32 + ln31;
      #pragma unroll
      for (int r = 0; r < 4; ++r) {
        float v0 = src[(size_t)(2 * r) * R_TOTAL];
        float v1 = src[(size_t)(2 * r + 1) * R_TOTAL];
        Ah[t][s].u[r] = pack_trunc(v0, v1);
        float h0 = __uint_as_float(__float_as_uint(v0) & 0xffff0000u);
        float h1 = __uint_as_float(__float_as_uint(v1) & 0xffff0000u);
        Al[t][s].u[r] = pack_trunc(v0 - h0, v1 - h1);
      }
    }

  f32x16 acc[2];
  #pragma unroll
  for (int t = 0; t < 2; ++t)
    #pragma unroll
    for (int i = 0; i < 16; ++i) acc[t][i] = 0.f;

  // this wave's K-quarter units: sub-k sk = h*2+s at wq + h*4096 + s*512
  const u32* wq = wt + (((size_t)(kq * HK) * 4 + nq) * 2) * 512;
  stage2k(wq, mybuf, lane);

  int sk = 0;
  for (int h = 0; h < HK; ++h) {
    const float* xlrow = xt + (size_t)(kq * HK + h) * R_TOTAL + r0 + 4 * q2;
    #pragma unroll
    for (int s = 0; s < 2; ++s, ++sk) {
      const int cur = sk & 1;
      __builtin_amdgcn_s_waitcnt(0x0F70);   // vmcnt(0): sub-k tile ready
      const u32* buf = mybuf + cur * 512;
      PackB bh, bl;
      bh.v = *(const u32x4*)(buf + q2 * 128 + ln31 * 4);
      bl.v = *(const u32x4*)(buf + 256 + q2 * 128 + ln31 * 4);
      if (sk + 1 < 2 * HK) {
        const int nsk = sk + 1;
        stage2k(wq + (size_t)(nsk >> 1) * 4096 + (size_t)(nsk & 1) * 512,
                mybuf + (1 - cur) * 512, lane);
      }
      #pragma unroll
      for (int t = 0; t < 2; ++t) {
        f32x4 xq[4];
        #pragma unroll
        for (int g = 0; g < 4; ++g)
          xq[g] = *(const f32x4*)(xlrow + t * 32 + 8 * g);
        f32x16 Y;
        #pragma unroll
        for (int i = 0; i < 16; ++i) Y[i] = 0.f;
        Y = __builtin_amdgcn_mfma_f32_32x32x16_bf16(Ah[t][s].s, bh.s, Y, 0, 0, 0);
        Y = __builtin_amdgcn_mfma_f32_32x32x16_bf16(Ah[t][s].s, bl.s, Y, 0, 0, 0);
        Y = __builtin_amdgcn_mfma_f32_32x32x16_bf16(Al[t][s].s, bh.s, Y, 0, 0, 0);
        #pragma unroll
        for (int i = 0; i < 16; ++i)
          acc[t][i] += xq[i >> 2][i & 3] * Y[i];
      }
    }
  }

  // ---------------- epilogue: kq tree-reduction + bias/relu/osum/store -------
  __syncthreads();
  if (kq & 1) {                       // kq1 -> region nq; kq3 -> region 4+nq
    u32* reg = smem + ((size_t)((kq >> 1) * 4 + nq)) * 2048;
    #pragma unroll
    for (int t = 0; t < 2; ++t)
      #pragma unroll
      for (int g = 0; g < 4; ++g)
        *(f32x4*)(reg + ((size_t)(t * 4 + g) * 64 + lane) * 4) =
            f32x4{acc[t][g * 4 + 0], acc[t][g * 4 + 1],
                  acc[t][g * 4 + 2], acc[t][g * 4 + 3]};
  }
  __syncthreads();
  if (!(kq & 1)) {                    // kq0 += region nq; kq2 += region 4+nq
    const u32* reg = smem + ((size_t)((kq >> 1) * 4 + nq)) * 2048;
    #pragma unroll
    for (int t = 0; t < 2; ++t)
      #pragma unroll
      for (int g = 0; g < 4; ++g) {
        f32x4 part = *(const f32x4*)(reg + ((size_t)(t * 4 + g) * 64 + lane) * 4);
        acc[t][g * 4 + 0] += part.x; acc[t][g * 4 + 1] += part.y;
        acc[t][g * 4 + 2] += part.z; acc[t][g * 4 + 3] += part.w;
      }
  }
  __syncthreads();
  if (kq == 2) {                      // dump merged (kq2+kq3) into region 4+nq
    u32* reg = smem + ((size_t)(4 + nq)) * 2048;
    #pragma unroll
    for (int t = 0; t < 2; ++t)
      #pragma unroll
      for (int g = 0; g < 4; ++g)
        *(f32x4*)(reg + ((size_t)(t * 4 + g) * 64 + lane) * 4) =
            f32x4{acc[t][g * 4 + 0], acc[t][g * 4 + 1],
                  acc[t][g * 4 + 2], acc[t][g * 4 + 3]};
  }
  __syncthreads();
  if (kq == 0) {
    const u32* reg = smem + ((size_t)(4 + nq)) * 2048;
    const float bs = bias[nq * 32 + ln31];
    #pragma unroll
    for (int t = 0; t < 2; ++t) {
      #pragma unroll
      for (int g = 0; g < 4; ++g) {
        f32x4 part = *(const f32x4*)(reg + ((size_t)(t * 4 + g) * 64 + lane) * 4);
        acc[t][g * 4 + 0] += part.x; acc[t][g * 4 + 1] += part.y;
        acc[t][g * 4 + 2] += part.z; acc[t][g * 4 + 3] += part.w;
      }
      #pragma unroll
      for (int i = 0; i < 16; ++i) {
        float v = acc[t][i] + bs;
        if (RELU) v = fmaxf(v, 0.f);
        acc[t][i] = v;
      }
      // d-sum: regs 0..7 -> batch t*2+0, regs 8..15 -> batch t*2+1
      float s0 = 0.f, s1 = 0.f;
      #pragma unroll
      for (int i = 0; i < 8; ++i) { s0 += acc[t][i]; s1 += acc[t][8 + i]; }
      s0 += __shfl_xor(s0, 32, 64);
      s1 += __shfl_xor(s1, 32, 64);
      const int col = nq * 32 + ln31;
      if (q2 == 0) {
        osum[(size_t)((r0 >> 4) + t * 2 + 0) * 384 + col] = s0;
        osum[(size_t)((r0 >> 4) + t * 2 + 1) * 384 + col] = s1;
      }
      if (STORE_X) {
        #pragma unroll
        for (int g = 0; g < 4; ++g)
          *(f32x4*)&xoutT[(size_t)col * R_TOTAL + r0 + t * 32 + 8 * g + 4 * q2] =
              f32x4{acc[t][g * 4 + 0], acc[t][g * 4 + 1],
                    acc[t][g * 4 + 2], acc[t][g * 4 + 3]};
      }
    }
  }
}

extern "C" void kernel_launch(void* const* d_in, const int* in_sizes, int n_in,
                              void* d_out, int out_size, void* d_ws, size_t ws_size,
                              hipStream_t stream) {
  const float* in = (const float*)d_in[0];
  const float* W0 = (const float*)d_in[1];
  const float* b0 = (const float*)d_in[2];
  const float* W1 = (const float*)d_in[3];
  const float* b1 = (const float*)d_in[4];
  const float* W2 = (const float*)d_in[5];
  const float* b2 = (const float*)d_in[6];
  float* out = (float*)d_out;

  float* X0T = (float*)d_ws;                         // 32 x 16384   (2 MB)
  float* X1T = X0T + (size_t)32 * R_TOTAL;           // 128 x 16384  (8 MB)
  float* X2T = X1T + (size_t)128 * R_TOTAL;          // 128 x 16384  (8 MB)
  u32* Wt0 = (u32*)(X2T + (size_t)128 * R_TOTAL);    // 32*8*512 u32   (0.5 MB)
  u32* Wt1 = Wt0 + (size_t)32 * 8 * 512;             // 128*8*512 u32  (2 MB)
  u32* Wt2 = Wt1 + (size_t)128 * 8 * 512;            // 128*8*512 u32  (2 MB)
  // total ws: 22.5 MB

  build_x0t<<<128, 256, 0, stream>>>(in, X0T);
  swizzle_w<<<32, 256, 0, stream>>>(W0, Wt0);
  swizzle_w<<<128, 256, 0, stream>>>(W1, Wt1);
  swizzle_w<<<128, 256, 0, stream>>>(W2, Wt2);

  layer_mfma<32, true, true><<<256, 1024, 0, stream>>>(X0T, X0T, Wt0, b0, X1T, out + 0);
  layer_mfma<128, true, true><<<256, 1024, 0, stream>>>(X1T, X0T, Wt1, b1, X2T, out + 128);
  layer_mfma<128, false, false><<<256, 1024, 0, stream>>>(X2T, X0T, Wt2, b2, nullptr, out + 256);
}

// Round 5
// 352.343 us; speedup vs baseline: 2.2785x; 2.2785x over previous
//
#include <hip/hip_runtime.h>

// CIN_51539607712 — R5: 32x32x16 MFMA, 512-thr blocks (8 waves), 2 blocks/CU.
// out[r,n] = sum_h xl[r,h] * Y_h[r,n],  Y_h[r,n] = sum_m x0[r,m] W[h*32+m,n].
// Y via 3 bf16 MFMAs (x0h*wh + x0h*wl + x0l*wh); acc += xl (.) Y in fp32.
// Block = 64 rows x 64 cols: waves (kq = w>>1 K-quarter, nh = w&1 N-32-half).
// Grid = 512 (row-block rb = bid>>1, col-half ch = bid&1); wave col-quarter
// nq = ch*2+nh. Per-wave 2-deep 2KB staging ring, barrier-free K-loop
// (per-wave vmcnt(0) only). LDS = 32 KB -> 2 blocks/CU = 4 waves/SIMD.
// NOTE: __launch_bounds__ arg2 measured to behave as min BLOCKS per CU on this
// toolchain ((1024,4) gave VGPR=64 + full spill in R4). (512,2) -> cap 128.

typedef unsigned int u32;
typedef __attribute__((ext_vector_type(8))) short short8;
typedef __attribute__((ext_vector_type(4))) float f32x4;
typedef __attribute__((ext_vector_type(16))) float f32x16;
typedef __attribute__((ext_vector_type(4))) u32 u32x4;

#define R_TOTAL 16384
#define GLOBAL_AS __attribute__((address_space(1)))
#define LDS_AS __attribute__((address_space(3)))

union PackU { u32 u[4]; short8 s; };
union PackB { u32x4 v; short8 s; };

__device__ __forceinline__ u32 pack_trunc(float a, float b) {
  return __builtin_amdgcn_perm(__float_as_uint(b), __float_as_uint(a), 0x07060302u);
}

// ---------------- prep: X0T[m][b*16+d] = in[b][m][d]  (32 x 16384) ----------
__global__ __launch_bounds__(256) void build_x0t(const float* __restrict__ in,
                                                 float* __restrict__ x0t) {
  __shared__ float t[4096];
  const int tid = threadIdx.x;
  const int b0 = blockIdx.x * 8;
  #pragma unroll
  for (int rep = 0; rep < 4; ++rep) {
    int idx = tid + rep * 256;
    *(float4*)&t[idx * 4] = *(const float4*)&in[(size_t)b0 * 512 + idx * 4];
  }
  __syncthreads();
  #pragma unroll
  for (int rep = 0; rep < 4; ++rep) {
    int idx = tid + rep * 256;     // 0..1023: m(32) x bl(8) x dq(4)
    int m = idx >> 5, rem = idx & 31;
    int bl = rem >> 2, dq = rem & 3;
    *(float4*)&x0t[(size_t)m * R_TOTAL + (b0 + bl) * 16 + dq * 4] =
        *(const float4*)&t[bl * 512 + m * 16 + dq * 4];
  }
}

// ---------------- prep: split+pack W into 2 KB sub-k units -------------------
// Unit (h, nq, s) at u32-offset ((h*4+nq)*2+s)*512. Entry e = p*64+q2*32+n
// (16 B): bf16 pairs (k=2r,2r+1) of part p of W[h*32+s*16+q2*8+(0..7)][nq*32+n].
__global__ __launch_bounds__(256) void swizzle_w(const float* __restrict__ W,
                                                 u32* __restrict__ wt) {
  __shared__ float wl[32 * 132];
  const int tid = threadIdx.x;
  const int h = blockIdx.x;
  #pragma unroll
  for (int rep = 0; rep < 4; ++rep) {
    int idx = tid + rep * 256;          // 1024 float4 = 32 k x 32 f4
    int kk = idx >> 5, c4 = idx & 31;
    *(float4*)&wl[kk * 132 + c4 * 4] =
        *(const float4*)&W[(size_t)(h * 32 + kk) * 128 + c4 * 4];
  }
  __syncthreads();
  #pragma unroll
  for (int rep = 0; rep < 4; ++rep) {
    int e = tid + rep * 256;            // 1024 entries (4 nq x 2 s x 128)
    int nq = e >> 8, rem = e & 255;
    int s = rem >> 7, p = (rem >> 6) & 1, q2 = (rem >> 5) & 1, n = rem & 31;
    int k0 = s * 16 + q2 * 8, col = nq * 32 + n;
    u32 o[4];
    #pragma unroll
    for (int r = 0; r < 4; ++r) {
      float v0 = wl[(k0 + 2 * r) * 132 + col];
      float v1 = wl[(k0 + 2 * r + 1) * 132 + col];
      if (p == 1) {
        v0 -= __uint_as_float(__float_as_uint(v0) & 0xffff0000u);
        v1 -= __uint_as_float(__float_as_uint(v1) & 0xffff0000u);
      }
      o[r] = pack_trunc(v0, v1);
    }
    *(u32x4*)(wt + (((size_t)h * 4 + nq) * 2 + s) * 512 + (rem & 127) * 4) =
        u32x4{o[0], o[1], o[2], o[3]};
  }
}

// ---------------- per-wave sub-k staging: 2048 B via global_load_lds ---------
__device__ __forceinline__ void stage2k(const u32* g, u32* l, int lane) {
  const GLOBAL_AS u32* gp = (const GLOBAL_AS u32*)g;
  LDS_AS u32* lp = (LDS_AS u32*)l;
  __builtin_amdgcn_global_load_lds(gp + lane * 4, lp, 16, 0, 0);
  __builtin_amdgcn_global_load_lds(gp + 256 + lane * 4, lp + 256, 16, 0, 0);
}

// ---------------- main layer kernel ----------------
template <int NT, bool RELU, bool STORE_X>
__global__ __launch_bounds__(512, 2) void layer_mfma(
    const float* __restrict__ xt,    // NT x R (transposed prev activation)
    const float* __restrict__ x0t,   // 32 x R
    const u32* __restrict__ wt,      // NT*8 sub-k units (512 u32 each)
    const float* __restrict__ bias,  // 128
    float* __restrict__ xoutT,       // 128 x R (if STORE_X)
    float* __restrict__ osum)        // d_out + layer offset, stride 384
{
  constexpr int HK = NT / 4;          // h-values per K-quarter
  __shared__ u32 smem[8192];          // 32 KB: 8 waves x (2 x 2KB ring)

  const int tid = threadIdx.x;
  const int w = tid >> 6, lane = tid & 63;
  const int kq = w >> 1, nh = w & 1;
  const int ln31 = lane & 31, q2 = lane >> 5;
  const int rb = blockIdx.x >> 1, ch = blockIdx.x & 1;
  const int nq = ch * 2 + nh;         // global col-quarter 0..3
  const int r0 = rb * 64;
  u32* mybuf = smem + w * 1024;

  // ---- loop-invariant A fragments: x0 splits. A[m=ln31][k=q2*8+j] per (t,s).
  PackU Ah[2][2], Al[2][2];
  #pragma unroll
  for (int t = 0; t < 2; ++t)
    #pragma unroll
    for (int s = 0; s < 2; ++s) {
      const float* src = x0t + (size_t)(s * 16 + q2 * 8) * R_TOTAL + r0 + t * 32 + ln31;
      #pragma unroll
      for (int r = 0; r < 4; ++r) {
        float v0 = src[(size_t)(2 * r) * R_TOTAL];
        float v1 = src[(size_t)(2 * r + 1) * R_TOTAL];
        Ah[t][s].u[r] = pack_trunc(v0, v1);
        float h0 = __uint_as_float(__float_as_uint(v0) & 0xffff0000u);
        float h1 = __uint_as_float(__float_as_uint(v1) & 0xffff0000u);
        Al[t][s].u[r] = pack_trunc(v0 - h0, v1 - h1);
      }
    }

  f32x16 acc[2];
  #pragma unroll
  for (int t = 0; t < 2; ++t)
    #pragma unroll
    for (int i = 0; i < 16; ++i) acc[t][i] = 0.f;

  // this wave's K-quarter units: sub-k sk = h*2+s at wq + h*4096 + s*512
  const u32* wq = wt + (((size_t)(kq * HK) * 4 + nq) * 2) * 512;
  stage2k(wq, mybuf, lane);

  int sk = 0;
  for (int h = 0; h < HK; ++h) {
    const float* xlrow = xt + (size_t)(kq * HK + h) * R_TOTAL + r0 + 4 * q2;
    #pragma unroll
    for (int s = 0; s < 2; ++s, ++sk) {
      const int cur = sk & 1;
      __builtin_amdgcn_s_waitcnt(0x0F70);   // vmcnt(0): sub-k tile ready
      const u32* buf = mybuf + cur * 512;
      PackB bh, bl;
      bh.v = *(const u32x4*)(buf + q2 * 128 + ln31 * 4);
      bl.v = *(const u32x4*)(buf + 256 + q2 * 128 + ln31 * 4);
      if (sk + 1 < 2 * HK) {
        const int nsk = sk + 1;
        stage2k(wq + (size_t)(nsk >> 1) * 4096 + (size_t)(nsk & 1) * 512,
                mybuf + (1 - cur) * 512, lane);
      }
      #pragma unroll
      for (int t = 0; t < 2; ++t) {
        f32x4 xq[4];
        #pragma unroll
        for (int g = 0; g < 4; ++g)
          xq[g] = *(const f32x4*)(xlrow + t * 32 + 8 * g);
        f32x16 Y;
        #pragma unroll
        for (int i = 0; i < 16; ++i) Y[i] = 0.f;
        Y = __builtin_amdgcn_mfma_f32_32x32x16_bf16(Ah[t][s].s, bh.s, Y, 0, 0, 0);
        Y = __builtin_amdgcn_mfma_f32_32x32x16_bf16(Ah[t][s].s, bl.s, Y, 0, 0, 0);
        Y = __builtin_amdgcn_mfma_f32_32x32x16_bf16(Al[t][s].s, bh.s, Y, 0, 0, 0);
        #pragma unroll
        for (int i = 0; i < 16; ++i)
          acc[t][i] += xq[i >> 2][i & 3] * Y[i];
      }
    }
  }

  // ---------------- epilogue: kq tree-reduction + bias/relu/osum/store -------
  // Regions: 4 x 2048 u32 (8 KB): region(i) = smem + i*2048.
  __syncthreads();
  if (kq & 1) {                       // kq1 -> region(nh); kq3 -> region(2+nh)
    u32* reg = smem + ((size_t)((kq >> 1) * 2 + nh)) * 2048;
    #pragma unroll
    for (int t = 0; t < 2; ++t)
      #pragma unroll
      for (int g = 0; g < 4; ++g)
        *(f32x4*)(reg + ((size_t)(t * 4 + g) * 64 + lane) * 4) =
            f32x4{acc[t][g * 4 + 0], acc[t][g * 4 + 1],
                  acc[t][g * 4 + 2], acc[t][g * 4 + 3]};
  }
  __syncthreads();
  if (!(kq & 1)) {                    // kq0 += region(nh); kq2 += region(2+nh)
    const u32* reg = smem + ((size_t)((kq >> 1) * 2 + nh)) * 2048;
    #pragma unroll
    for (int t = 0; t < 2; ++t)
      #pragma unroll
      for (int g = 0; g < 4; ++g) {
        f32x4 part = *(const f32x4*)(reg + ((size_t)(t * 4 + g) * 64 + lane) * 4);
        acc[t][g * 4 + 0] += part.x; acc[t][g * 4 + 1] += part.y;
        acc[t][g * 4 + 2] += part.z; acc[t][g * 4 + 3] += part.w;
      }
  }
  __syncthreads();
  if (kq == 2) {                      // dump merged (kq2+kq3) into region(2+nh)
    u32* reg = smem + ((size_t)(2 + nh)) * 2048;
    #pragma unroll
    for (int t = 0; t < 2; ++t)
      #pragma unroll
      for (int g = 0; g < 4; ++g)
        *(f32x4*)(reg + ((size_t)(t * 4 + g) * 64 + lane) * 4) =
            f32x4{acc[t][g * 4 + 0], acc[t][g * 4 + 1],
                  acc[t][g * 4 + 2], acc[t][g * 4 + 3]};
  }
  __syncthreads();
  if (kq == 0) {
    const u32* reg = smem + ((size_t)(2 + nh)) * 2048;
    const float bs = bias[nq * 32 + ln31];
    #pragma unroll
    for (int t = 0; t < 2; ++t) {
      #pragma unroll
      for (int g = 0; g < 4; ++g) {
        f32x4 part = *(const f32x4*)(reg + ((size_t)(t * 4 + g) * 64 + lane) * 4);
        acc[t][g * 4 + 0] += part.x; acc[t][g * 4 + 1] += part.y;
        acc[t][g * 4 + 2] += part.z; acc[t][g * 4 + 3] += part.w;
      }
      #pragma unroll
      for (int i = 0; i < 16; ++i) {
        float v = acc[t][i] + bs;
        if (RELU) v = fmaxf(v, 0.f);
        acc[t][i] = v;
      }
      // d-sum: regs 0..7 -> batch t*2+0, regs 8..15 -> batch t*2+1
      float s0 = 0.f, s1 = 0.f;
      #pragma unroll
      for (int i = 0; i < 8; ++i) { s0 += acc[t][i]; s1 += acc[t][8 + i]; }
      s0 += __shfl_xor(s0, 32, 64);
      s1 += __shfl_xor(s1, 32, 64);
      const int col = nq * 32 + ln31;
      if (q2 == 0) {
        osum[(size_t)((r0 >> 4) + t * 2 + 0) * 384 + col] = s0;
        osum[(size_t)((r0 >> 4) + t * 2 + 1) * 384 + col] = s1;
      }
      if (STORE_X) {
        #pragma unroll
        for (int g = 0; g < 4; ++g)
          *(f32x4*)&xoutT[(size_t)col * R_TOTAL + r0 + t * 32 + 8 * g + 4 * q2] =
              f32x4{acc[t][g * 4 + 0], acc[t][g * 4 + 1],
                    acc[t][g * 4 + 2], acc[t][g * 4 + 3]};
      }
    }
  }
}

extern "C" void kernel_launch(void* const* d_in, const int* in_sizes, int n_in,
                              void* d_out, int out_size, void* d_ws, size_t ws_size,
                              hipStream_t stream) {
  const float* in = (const float*)d_in[0];
  const float* W0 = (const float*)d_in[1];
  const float* b0 = (const float*)d_in[2];
  const float* W1 = (const float*)d_in[3];
  const float* b1 = (const float*)d_in[4];
  const float* W2 = (const float*)d_in[5];
  const float* b2 = (const float*)d_in[6];
  float* out = (float*)d_out;

  float* X0T = (float*)d_ws;                         // 32 x 16384   (2 MB)
  float* X1T = X0T + (size_t)32 * R_TOTAL;           // 128 x 16384  (8 MB)
  float* X2T = X1T + (size_t)128 * R_TOTAL;          // 128 x 16384  (8 MB)
  u32* Wt0 = (u32*)(X2T + (size_t)128 * R_TOTAL);    // 32*8*512 u32   (0.5 MB)
  u32* Wt1 = Wt0 + (size_t)32 * 8 * 512;             // 128*8*512 u32  (2 MB)
  u32* Wt2 = Wt1 + (size_t)128 * 8 * 512;            // 128*8*512 u32  (2 MB)
  // total ws: 22.5 MB

  build_x0t<<<128, 256, 0, stream>>>(in, X0T);
  swizzle_w<<<32, 256, 0, stream>>>(W0, Wt0);
  swizzle_w<<<128, 256, 0, stream>>>(W1, Wt1);
  swizzle_w<<<128, 256, 0, stream>>>(W2, Wt2);

  layer_mfma<32, true, true><<<512, 512, 0, stream>>>(X0T, X0T, Wt0, b0, X1T, out + 0);
  layer_mfma<128, true, true><<<512, 512, 0, stream>>>(X1T, X0T, Wt1, b1, X2T, out + 128);
  layer_mfma<128, false, false><<<512, 512, 0, stream>>>(X2T, X0T, Wt2, b2, nullptr, out + 256);
}

// Round 6
// 206.064 us; speedup vs baseline: 3.8959x; 1.7099x over previous
//
#include <hip/hip_runtime.h>

// CIN_51539607712 — R6: z-split MFMA (A = split(xl*x0) per iter, acc in-place).
// out[r,n] = act( sum_k z[r,k] W[k,n] + b ), z[r,h*32+m] = xl[r,h]*x0[r,m].
// z computed fp32-exact per sub-k, split z = zh + zl (bf16 each); 3 MFMAs
// (zh*Wh + zh*Wl + zl*Wh) accumulate IN PLACE into fp32 acc -> no VALU-live
// Y/xq transients (R5's 128-cap spill eliminated).
// Block = 64 rows x 64 cols, 512 thr = 8 waves: (kq = w>>1, nh = w&1).
// Grid = 512 (row-block rb = bid>>1, col-half ch = bid&1); nq = ch*2+nh.
// Per-wave 2-deep 2KB staging ring via global_load_lds, barrier-free K-loop
// (per-wave vmcnt(0) only). LDS = 32 KB -> 2 blocks/CU = 4 waves/SIMD.
// NOTE: __launch_bounds__ arg2 behaves as min BLOCKS per CU on this toolchain
// ((1024,4) gave VGPR=64 + full spill in R4). (512,2) -> cap 128 VGPR.

typedef unsigned int u32;
typedef __attribute__((ext_vector_type(8))) short short8;
typedef __attribute__((ext_vector_type(4))) float f32x4;
typedef __attribute__((ext_vector_type(16))) float f32x16;
typedef __attribute__((ext_vector_type(4))) u32 u32x4;

#define R_TOTAL 16384
#define GLOBAL_AS __attribute__((address_space(1)))
#define LDS_AS __attribute__((address_space(3)))

union PackU { u32 u[4]; short8 s; };
union PackB { u32x4 v; short8 s; };

__device__ __forceinline__ u32 pack_trunc(float a, float b) {
  return __builtin_amdgcn_perm(__float_as_uint(b), __float_as_uint(a), 0x07060302u);
}

// ---------------- prep: X0T[m][b*16+d] = in[b][m][d]  (32 x 16384) ----------
__global__ __launch_bounds__(256) void build_x0t(const float* __restrict__ in,
                                                 float* __restrict__ x0t) {
  __shared__ float t[4096];
  const int tid = threadIdx.x;
  const int b0 = blockIdx.x * 8;
  #pragma unroll
  for (int rep = 0; rep < 4; ++rep) {
    int idx = tid + rep * 256;
    *(float4*)&t[idx * 4] = *(const float4*)&in[(size_t)b0 * 512 + idx * 4];
  }
  __syncthreads();
  #pragma unroll
  for (int rep = 0; rep < 4; ++rep) {
    int idx = tid + rep * 256;     // 0..1023: m(32) x bl(8) x dq(4)
    int m = idx >> 5, rem = idx & 31;
    int bl = rem >> 2, dq = rem & 3;
    *(float4*)&x0t[(size_t)m * R_TOTAL + (b0 + bl) * 16 + dq * 4] =
        *(const float4*)&t[bl * 512 + m * 16 + dq * 4];
  }
}

// ---------------- prep: split+pack W into 2 KB sub-k units -------------------
// Unit (h, nq, s) at u32-offset ((h*4+nq)*2+s)*512. Entry e = p*64+q2*32+n
// (16 B): bf16 pairs (k=2r,2r+1) of part p of W[h*32+s*16+q2*8+(0..7)][nq*32+n].
__global__ __launch_bounds__(256) void swizzle_w(const float* __restrict__ W,
                                                 u32* __restrict__ wt) {
  __shared__ float wl[32 * 132];
  const int tid = threadIdx.x;
  const int h = blockIdx.x;
  #pragma unroll
  for (int rep = 0; rep < 4; ++rep) {
    int idx = tid + rep * 256;          // 1024 float4 = 32 k x 32 f4
    int kk = idx >> 5, c4 = idx & 31;
    *(float4*)&wl[kk * 132 + c4 * 4] =
        *(const float4*)&W[(size_t)(h * 32 + kk) * 128 + c4 * 4];
  }
  __syncthreads();
  #pragma unroll
  for (int rep = 0; rep < 4; ++rep) {
    int e = tid + rep * 256;            // 1024 entries (4 nq x 2 s x 128)
    int nq = e >> 8, rem = e & 255;
    int s = rem >> 7, p = (rem >> 6) & 1, q2 = (rem >> 5) & 1, n = rem & 31;
    int k0 = s * 16 + q2 * 8, col = nq * 32 + n;
    u32 o[4];
    #pragma unroll
    for (int r = 0; r < 4; ++r) {
      float v0 = wl[(k0 + 2 * r) * 132 + col];
      float v1 = wl[(k0 + 2 * r + 1) * 132 + col];
      if (p == 1) {
        v0 -= __uint_as_float(__float_as_uint(v0) & 0xffff0000u);
        v1 -= __uint_as_float(__float_as_uint(v1) & 0xffff0000u);
      }
      o[r] = pack_trunc(v0, v1);
    }
    *(u32x4*)(wt + (((size_t)h * 4 + nq) * 2 + s) * 512 + (rem & 127) * 4) =
        u32x4{o[0], o[1], o[2], o[3]};
  }
}

// ---------------- per-wave sub-k staging: 2048 B via global_load_lds ---------
__device__ __forceinline__ void stage2k(const u32* g, u32* l, int lane) {
  const GLOBAL_AS u32* gp = (const GLOBAL_AS u32*)g;
  LDS_AS u32* lp = (LDS_AS u32*)l;
  __builtin_amdgcn_global_load_lds(gp + lane * 4, lp, 16, 0, 0);
  __builtin_amdgcn_global_load_lds(gp + 256 + lane * 4, lp + 256, 16, 0, 0);
}

// ---------------- main layer kernel ----------------
template <int NT, bool RELU, bool STORE_X>
__global__ __launch_bounds__(512, 2) void layer_mfma(
    const float* __restrict__ xt,    // NT x R (transposed prev activation)
    const float* __restrict__ x0t,   // 32 x R
    const u32* __restrict__ wt,      // NT*8 sub-k units (512 u32 each)
    const float* __restrict__ bias,  // 128
    float* __restrict__ xoutT,       // 128 x R (if STORE_X)
    float* __restrict__ osum)        // d_out + layer offset, stride 384
{
  constexpr int HK = NT / 4;          // h-values per K-quarter
  __shared__ u32 smem[8192];          // 32 KB: 8 waves x (2 x 2KB ring)

  const int tid = threadIdx.x;
  const int w = tid >> 6, lane = tid & 63;
  const int kq = w >> 1, nh = w & 1;
  const int ln31 = lane & 31, q2 = lane >> 5;
  const int rb = blockIdx.x >> 1, ch = blockIdx.x & 1;
  const int nq = ch * 2 + nh;         // global col-quarter 0..3
  const int r0 = rb * 64;
  u32* mybuf = smem + w * 1024;

  // ---- loop-invariant fp32 x0 values: x0v[t][s][j] = x0[r,(s*16+q2*8+j)],
  //      r = r0 + t*32 + ln31 (this lane's A-row for tile t).
  float x0v[2][2][8];
  #pragma unroll
  for (int t = 0; t < 2; ++t)
    #pragma unroll
    for (int s = 0; s < 2; ++s)
      #pragma unroll
      for (int j = 0; j < 8; ++j)
        x0v[t][s][j] =
            x0t[(size_t)(s * 16 + q2 * 8 + j) * R_TOTAL + r0 + t * 32 + ln31];

  f32x16 acc[2];
  #pragma unroll
  for (int t = 0; t < 2; ++t)
    #pragma unroll
    for (int i = 0; i < 16; ++i) acc[t][i] = 0.f;

  // this wave's K-quarter units: sub-k sk = h*2+s at wq + h*4096 + s*512
  const u32* wq = wt + (((size_t)(kq * HK) * 4 + nq) * 2) * 512;
  stage2k(wq, mybuf, lane);

  const float* xlbase = xt + (size_t)(kq * HK) * R_TOTAL + r0 + ln31;
  float xl0 = xlbase[0], xl1 = xlbase[32];

  int sk = 0;
  #pragma unroll 1
  for (int h = 0; h < HK; ++h) {
    const float xc0 = xl0, xc1 = xl1;
    #pragma unroll
    for (int s = 0; s < 2; ++s, ++sk) {
      __builtin_amdgcn_s_waitcnt(0x0F70);   // vmcnt(0): tile sk + loads ready
      const u32* buf = mybuf + (sk & 1) * 512;
      PackB bh, bl;
      bh.v = *(const u32x4*)(buf + q2 * 128 + ln31 * 4);
      bl.v = *(const u32x4*)(buf + 256 + q2 * 128 + ln31 * 4);
      if (sk + 1 < 2 * HK) {
        const int nsk = sk + 1;
        stage2k(wq + (size_t)(nsk >> 1) * 4096 + (size_t)(nsk & 1) * 512,
                mybuf + (1 - (sk & 1)) * 512, lane);
      }
      if (s == 0 && h + 1 < HK) {           // prefetch xl for next h
        const float* p = xlbase + (size_t)(h + 1) * R_TOTAL;
        xl0 = p[0];
        xl1 = p[32];
      }
      #pragma unroll
      for (int t = 0; t < 2; ++t) {
        const float xc = t ? xc1 : xc0;
        PackU Ah, Al;
        #pragma unroll
        for (int r = 0; r < 4; ++r) {
          float z0 = xc * x0v[t][s][2 * r + 0];
          float z1 = xc * x0v[t][s][2 * r + 1];
          Ah.u[r] = pack_trunc(z0, z1);
          float h0 = __uint_as_float(__float_as_uint(z0) & 0xffff0000u);
          float h1 = __uint_as_float(__float_as_uint(z1) & 0xffff0000u);
          Al.u[r] = pack_trunc(z0 - h0, z1 - h1);
        }
        acc[t] = __builtin_amdgcn_mfma_f32_32x32x16_bf16(Ah.s, bh.s, acc[t], 0, 0, 0);
        acc[t] = __builtin_amdgcn_mfma_f32_32x32x16_bf16(Ah.s, bl.s, acc[t], 0, 0, 0);
        acc[t] = __builtin_amdgcn_mfma_f32_32x32x16_bf16(Al.s, bh.s, acc[t], 0, 0, 0);
      }
    }
  }

  // ---------------- epilogue: kq tree-reduction + bias/relu/osum/store -------
  // Regions: 4 x 2048 u32 (8 KB): region(i) = smem + i*2048.
  __syncthreads();
  if (kq & 1) {                       // kq1 -> region(nh); kq3 -> region(2+nh)
    u32* reg = smem + ((size_t)((kq >> 1) * 2 + nh)) * 2048;
    #pragma unroll
    for (int t = 0; t < 2; ++t)
      #pragma unroll
      for (int g = 0; g < 4; ++g)
        *(f32x4*)(reg + ((size_t)(t * 4 + g) * 64 + lane) * 4) =
            f32x4{acc[t][g * 4 + 0], acc[t][g * 4 + 1],
                  acc[t][g * 4 + 2], acc[t][g * 4 + 3]};
  }
  __syncthreads();
  if (!(kq & 1)) {                    // kq0 += region(nh); kq2 += region(2+nh)
    const u32* reg = smem + ((size_t)((kq >> 1) * 2 + nh)) * 2048;
    #pragma unroll
    for (int t = 0; t < 2; ++t)
      #pragma unroll
      for (int g = 0; g < 4; ++g) {
        f32x4 part = *(const f32x4*)(reg + ((size_t)(t * 4 + g) * 64 + lane) * 4);
        acc[t][g * 4 + 0] += part.x; acc[t][g * 4 + 1] += part.y;
        acc[t][g * 4 + 2] += part.z; acc[t][g * 4 + 3] += part.w;
      }
  }
  __syncthreads();
  if (kq == 2) {                      // dump merged (kq2+kq3) into region(2+nh)
    u32* reg = smem + ((size_t)(2 + nh)) * 2048;
    #pragma unroll
    for (int t = 0; t < 2; ++t)
      #pragma unroll
      for (int g = 0; g < 4; ++g)
        *(f32x4*)(reg + ((size_t)(t * 4 + g) * 64 + lane) * 4) =
            f32x4{acc[t][g * 4 + 0], acc[t][g * 4 + 1],
                  acc[t][g * 4 + 2], acc[t][g * 4 + 3]};
  }
  __syncthreads();
  if (kq == 0) {
    const u32* reg = smem + ((size_t)(2 + nh)) * 2048;
    const float bs = bias[nq * 32 + ln31];
    #pragma unroll
    for (int t = 0; t < 2; ++t) {
      #pragma unroll
      for (int g = 0; g < 4; ++g) {
        f32x4 part = *(const f32x4*)(reg + ((size_t)(t * 4 + g) * 64 + lane) * 4);
        acc[t][g * 4 + 0] += part.x; acc[t][g * 4 + 1] += part.y;
        acc[t][g * 4 + 2] += part.z; acc[t][g * 4 + 3] += part.w;
      }
      #pragma unroll
      for (int i = 0; i < 16; ++i) {
        float v = acc[t][i] + bs;
        if (RELU) v = fmaxf(v, 0.f);
        acc[t][i] = v;
      }
      // d-sum: regs 0..7 -> batch t*2+0, regs 8..15 -> batch t*2+1
      float s0 = 0.f, s1 = 0.f;
      #pragma unroll
      for (int i = 0; i < 8; ++i) { s0 += acc[t][i]; s1 += acc[t][8 + i]; }
      s0 += __shfl_xor(s0, 32, 64);
      s1 += __shfl_xor(s1, 32, 64);
      const int col = nq * 32 + ln31;
      if (q2 == 0) {
        osum[(size_t)((r0 >> 4) + t * 2 + 0) * 384 + col] = s0;
        osum[(size_t)((r0 >> 4) + t * 2 + 1) * 384 + col] = s1;
      }
      if (STORE_X) {
        #pragma unroll
        for (int g = 0; g < 4; ++g)
          *(f32x4*)&xoutT[(size_t)col * R_TOTAL + r0 + t * 32 + 8 * g + 4 * q2] =
              f32x4{acc[t][g * 4 + 0], acc[t][g * 4 + 1],
                    acc[t][g * 4 + 2], acc[t][g * 4 + 3]};
      }
    }
  }
}

extern "C" void kernel_launch(void* const* d_in, const int* in_sizes, int n_in,
                              void* d_out, int out_size, void* d_ws, size_t ws_size,
                              hipStream_t stream) {
  const float* in = (const float*)d_in[0];
  const float* W0 = (const float*)d_in[1];
  const float* b0 = (const float*)d_in[2];
  const float* W1 = (const float*)d_in[3];
  const float* b1 = (const float*)d_in[4];
  const float* W2 = (const float*)d_in[5];
  const float* b2 = (const float*)d_in[6];
  float* out = (float*)d_out;

  float* X0T = (float*)d_ws;                         // 32 x 16384   (2 MB)
  float* X1T = X0T + (size_t)32 * R_TOTAL;           // 128 x 16384  (8 MB)
  float* X2T = X1T + (size_t)128 * R_TOTAL;          // 128 x 16384  (8 MB)
  u32* Wt0 = (u32*)(X2T + (size_t)128 * R_TOTAL);    // 32*8*512 u32   (0.5 MB)
  u32* Wt1 = Wt0 + (size_t)32 * 8 * 512;             // 128*8*512 u32  (2 MB)
  u32* Wt2 = Wt1 + (size_t)128 * 8 * 512;            // 128*8*512 u32  (2 MB)
  // total ws: 22.5 MB

  build_x0t<<<128, 256, 0, stream>>>(in, X0T);
  swizzle_w<<<32, 256, 0, stream>>>(W0, Wt0);
  swizzle_w<<<128, 256, 0, stream>>>(W1, Wt1);
  swizzle_w<<<128, 256, 0, stream>>>(W2, Wt2);

  layer_mfma<32, true, true><<<512, 512, 0, stream>>>(X0T, X0T, Wt0, b0, X1T, out + 0);
  layer_mfma<128, true, true><<<512, 512, 0, stream>>>(X1T, X0T, Wt1, b1, X2T, out + 128);
  layer_mfma<128, false, false><<<512, 512, 0, stream>>>(X2T, X0T, Wt2, b2, nullptr, out + 256);
}